// Round 13
// baseline (2400.673 us; speedup 1.0000x reference)
//
#include <hip/hip_runtime.h>
#include <math.h>

typedef _Float16 half8 __attribute__((ext_vector_type(8)));
typedef _Float16 half4 __attribute__((ext_vector_type(4)));
typedef float float4v __attribute__((ext_vector_type(4)));

constexpr int Lc   = 2048;  // L_IN
constexpr int DECc = 64;    // DEC_LEN
constexpr int Hc   = 128;   // H
constexpr int EMBc = 16;    // EMB
constexpr int INc  = 18;    // IN_SIZE
constexpr int NBc  = 4;     // batches per block
constexpr int NTc  = 256;   // 4 waves -> 1 wave/SIMD (R12)
constexpr int KT   = 5;     // k-tiles of 32 (z padded to 160)
constexpr int CARD = 200;
constexpr int ZS   = 160;   // z stride per batch (halves)
constexpr int SCS  = 136;   // shuffle-scratch row stride (halves): banks 4ab+2cl distinct

__device__ __forceinline__ float rcp_(float x) { return __builtin_amdgcn_rcpf(x); }
__device__ __forceinline__ float sigm(float x) { return rcp_(1.0f + __expf(-x)); }
__device__ __forceinline__ float tanh_(float x) { return 2.0f * rcp_(1.0f + __expf(-2.0f * x)) - 1.0f; }
__device__ __forceinline__ float softplus_(float x) { return __logf(1.0f + __expf(x)); }

// Transposed GEMM (verified R11): D[m=batch(rep)][n=gate] = z[m][k] * Wc^T[k][n],
// gate order g = 4*cell+gt. Wave wv owns gates 128wv..128wv+127 (8 tiles).
// C rows replicate batches mod 4 => any quad's reg r = batch r.

__global__ __launch_bounds__(NTc, 1) void rnnar_kernel(
    const int*   __restrict__ cat_in,  const float* __restrict__ cont_in,
    const float* __restrict__ X_in,    const int*   __restrict__ cat_out,
    const float* __restrict__ cont_out,const float* __restrict__ emb_table,
    const float* __restrict__ cont_w,
    const float* __restrict__ Wih_e, const float* __restrict__ Whh_e, const float* __restrict__ b_e,
    const float* __restrict__ Wih_d, const float* __restrict__ Whh_d, const float* __restrict__ b_d,
    const float* __restrict__ Wm, const float* __restrict__ bm,
    const float* __restrict__ Ws, const float* __restrict__ bs,
    const float* __restrict__ Wv, const float* __restrict__ bv,
    float* __restrict__ out)
{
    // ~59.6 KB total
    __shared__ _Float16      z_lds[2][NBc * ZS];   // 2.5 KB double-buffered z, [b][k]
    __shared__ _Float16      sc[4 * 4 * SCS];      // 4.3 KB per-wave gate shuffle scratch
    __shared__ _Float16      emb_lds[CARD * EMBc]; // 6.4 KB
    __shared__ _Float16      xs0[NBc * Lc];        // 16 KB cont_in * w00
    __shared__ _Float16      xs1[NBc * Lc];        // 16 KB X_in
    __shared__ _Float16      xo_lds[NBc * DECc];   // 512 B cont_out * w00
    __shared__ unsigned char catb[NBc * Lc];       // 8 KB
    __shared__ unsigned char catob[NBc * DECc];    // 256 B
    __shared__ float         h32_lds[NBc * 132];   // 2.1 KB
    __shared__ float         wh_lds[6 * Hc];       // 3 KB
    __shared__ float         hb_lds[8];

    const int tid  = threadIdx.x;
    const int lane = tid & 63;
    const int wv   = tid >> 6;        // wave 0..3
    const int q    = lane >> 4;       // quad 0..3
    const int col  = lane & 15;
    const int b0   = blockIdx.x * NBc;
    const float w00 = cont_w[0];

    const int xk = tid >> 2, xb = tid & 3;   // x-writer role (tid < 72)
    const int cl = lane >> 2;                // cell-local 0..15
    const int ab = lane & 3;                 // batch 0..3
    const int cellA = 32 * wv + cl;          // activation cells: cellA, cellA+16
    const int cellB = cellA + 16;

    // ---------------- staging ----------------
    {
        int* z32 = (int*)&z_lds[0][0];
        for (int i = tid; i < NBc * ZS; i += NTc) z32[i] = 0;  // covers both buffers (ints)
    }
    for (int i = tid; i < NBc * Lc; i += NTc) {
        const int b = i >> 11, t = i & (Lc - 1);
        catb[i] = (unsigned char)cat_in[(b0 + b) * Lc + t];
        xs0[i]  = (_Float16)(cont_in[(b0 + b) * Lc + t] * w00);
        xs1[i]  = (_Float16)(X_in[(b0 + b) * Lc + t]);
    }
    for (int i = tid; i < NBc * DECc; i += NTc) {
        const int b = i >> 6, t = i & 63;
        catob[i]  = (unsigned char)cat_out[(b0 + b) * DECc + t];
        xo_lds[i] = (_Float16)(cont_out[(b0 + b) * DECc + t] * w00);
    }
    for (int i = tid; i < CARD * EMBc; i += NTc) emb_lds[i] = (_Float16)emb_table[i];
    for (int i = tid; i < 6 * Hc; i += NTc) {
        const int o = i >> 7, k = i & 127;
        wh_lds[i] = (o == 0) ? Wm[k] : (o == 1) ? Ws[k] : Wv[(o - 2) * Hc + k];
    }
    if (tid == 0) { hb_lds[0] = bm[0]; hb_lds[1] = bs[0]; }
    if (tid < 4)  { hb_lds[2 + tid] = bv[tid]; }

    // ---- B-fragments: wave wv owns 8 gate-tiles (gates 128wv..128wv+127) ----
    half8 Bf[8][KT];
    float bias_s[8];
    #define LOAD_T(WIH, WHH, BB)                                               \
    {                                                                          \
        _Pragma("unroll")                                                      \
        for (int tile = 0; tile < 8; ++tile) {                                 \
            const int g   = 128 * wv + 16 * tile + col;                        \
            const int row = (g & 3) * Hc + (g >> 2);                           \
            _Pragma("unroll")                                                  \
            for (int kt = 0; kt < KT; ++kt) {                                  \
                half8 f;                                                       \
                _Pragma("unroll")                                              \
                for (int j = 0; j < 8; ++j) {                                  \
                    const int k = 32 * kt + 8 * q + j;                         \
                    float v = 0.0f;                                            \
                    if (k < INc)            v = WIH[row * INc + k];            \
                    else if (k < INc + Hc)  v = WHH[row * Hc + (k - INc)];     \
                    f[j] = (_Float16)v;                                        \
                }                                                              \
                Bf[tile][kt] = f;                                              \
            }                                                                  \
            bias_s[tile] = BB[row];                                            \
        }                                                                      \
    }

    LOAD_T(Wih_e, Whh_e, b_e);
    __syncthreads();

    // x(0) into buffer 0
    if (tid < INc * NBc) {
        _Float16 v;
        if (xk < EMBc)       v = emb_lds[(int)catb[xb * Lc] * EMBc + xk];
        else if (xk == EMBc) v = xs0[xb * Lc];
        else                 v = xs1[xb * Lc];
        z_lds[0][xb * ZS + xk] = v;
    }
    __syncthreads();

    int p = 0;
    float cA = 0.f, cB = 0.f;
    _Float16* scw = sc + wv * 4 * SCS;

    // ===================== encoder: 1 barrier/step =====================
    for (int t = 0; t < Lc; ++t) {
        const _Float16* zr = &z_lds[p][0];
        _Float16*       zw = &z_lds[p ^ 1][0];

        // A-frags from z (batch = col&3); 4-lane same-address broadcast
        const _Float16* ap = zr + (col & 3) * ZS + 8 * q;
        half8 Az[KT];
        #pragma unroll
        for (int kt = 0; kt < KT; ++kt) Az[kt] = *(const half8*)(ap + 32 * kt);

        float4v acc[8];
        #pragma unroll
        for (int tile = 0; tile < 8; ++tile) {
            float4v a = {bias_s[tile], bias_s[tile], bias_s[tile], bias_s[tile]};
            #pragma unroll
            for (int kt = 0; kt < KT; ++kt)
                a = __builtin_amdgcn_mfma_f32_16x16x32_f16(Az[kt], Bf[tile][kt], a, 0, 0, 0);
            acc[tile] = a;
        }

        // intra-wave shuffle: quad (tile&3) writes tile's 4 batch-rows (regs = batches)
        #pragma unroll
        for (int tile = 0; tile < 8; ++tile) {
            if (q == (tile & 3)) {
                #pragma unroll
                for (int r = 0; r < 4; ++r)
                    scw[r * SCS + 16 * tile + col] = (_Float16)acc[tile][r];
            }
        }
        // two cell-updates per thread: (cellA, ab), (cellB, ab)
        const half4 ga = *(const half4*)(scw + ab * SCS + 4 * cl);
        const half4 gb = *(const half4*)(scw + ab * SCS + 4 * cl + 64);
        {
            const float cn = sigm((float)ga[1]) * cA + sigm((float)ga[0]) * tanh_((float)ga[2]);
            cA = cn;
            zw[ab * ZS + INc + cellA] = (_Float16)(sigm((float)ga[3]) * tanh_(cn));
        }
        {
            const float cn = sigm((float)gb[1]) * cB + sigm((float)gb[0]) * tanh_((float)gb[2]);
            cB = cn;
            zw[ab * ZS + INc + cellB] = (_Float16)(sigm((float)gb[3]) * tanh_(cn));
        }

        // x(t+1) (clamped: t=Lc-1 writes decoder-init x)
        if (tid < INc * NBc) {
            const int t1 = (t + 1 < Lc) ? t + 1 : Lc - 1;
            _Float16 v;
            if (xk < EMBc)       v = emb_lds[(int)catb[xb * Lc + t1] * EMBc + xk];
            else if (xk == EMBc) v = xs0[xb * Lc + t1];
            else                 v = xs1[xb * Lc + t1];
            zw[xb * ZS + xk] = v;
        }
        __syncthreads();
        p ^= 1;
    }

    // ===================== decoder =====================
    LOAD_T(Wih_d, Whh_d, b_d);
    const float bm0 = hb_lds[0], bs0 = hb_lds[1];

    for (int t = 0; t < DECc; ++t) {
        const _Float16* zr = &z_lds[p][0];
        _Float16*       zw = &z_lds[p ^ 1][0];

        const _Float16* ap = zr + (col & 3) * ZS + 8 * q;
        half8 Az[KT];
        #pragma unroll
        for (int kt = 0; kt < KT; ++kt) Az[kt] = *(const half8*)(ap + 32 * kt);

        float4v acc[8];
        #pragma unroll
        for (int tile = 0; tile < 8; ++tile) {
            float4v a = {bias_s[tile], bias_s[tile], bias_s[tile], bias_s[tile]};
            #pragma unroll
            for (int kt = 0; kt < KT; ++kt)
                a = __builtin_amdgcn_mfma_f32_16x16x32_f16(Az[kt], Bf[tile][kt], a, 0, 0, 0);
            acc[tile] = a;
        }

        #pragma unroll
        for (int tile = 0; tile < 8; ++tile) {
            if (q == (tile & 3)) {
                #pragma unroll
                for (int r = 0; r < 4; ++r)
                    scw[r * SCS + 16 * tile + col] = (_Float16)acc[tile][r];
            }
        }
        const half4 ga = *(const half4*)(scw + ab * SCS + 4 * cl);
        const half4 gb = *(const half4*)(scw + ab * SCS + 4 * cl + 64);
        {
            const float cn = sigm((float)ga[1]) * cA + sigm((float)ga[0]) * tanh_((float)ga[2]);
            cA = cn;
            const float hv = sigm((float)ga[3]) * tanh_(cn);
            zw[ab * ZS + INc + cellA] = (_Float16)hv;
            h32_lds[ab * 132 + cellA] = hv;
        }
        {
            const float cn = sigm((float)gb[1]) * cB + sigm((float)gb[0]) * tanh_((float)gb[2]);
            cB = cn;
            const float hv = sigm((float)gb[3]) * tanh_(cn);
            zw[ab * ZS + INc + cellB] = (_Float16)hv;
            h32_lds[ab * 132 + cellB] = hv;
        }

        // feats_out(t) -> x(t+1); slot 17 (mu) written by heads
        if (tid < INc * NBc && xk < INc - 1) {
            _Float16 v;
            if (xk < EMBc) v = emb_lds[(int)catob[xb * DECc + t] * EMBc + xk];
            else           v = xo_lds[xb * DECc + t];
            zw[xb * ZS + xk] = v;
        }
        __syncthreads();

        // heads
        if (tid < NBc * 8) {
            const int b = tid >> 3, o = tid & 7;
            if (o < 6) {
                float s = 0.0f;
                #pragma unroll 8
                for (int k = 0; k < Hc; ++k) s += wh_lds[o * Hc + k] * h32_lds[b * 132 + k];
                const int gb2 = b0 + b;
                if (o == 0) {
                    const float mu = s + bm0;
                    out[gb2 * DECc + t] = mu;
                    zw[b * ZS + (INc - 1)] = (_Float16)mu;   // mu feedback
                } else if (o == 1) {
                    out[65536 + gb2 * DECc + t] = softplus_(s + bs0);
                } else {
                    out[131072 + (gb2 * DECc + t) * 4 + (o - 2)] = s + hb_lds[2 + (o - 2)];
                }
            }
        }
        __syncthreads();
        p ^= 1;
    }
    #undef LOAD_T
}

extern "C" void kernel_launch(void* const* d_in, const int* in_sizes, int n_in,
                              void* d_out, int out_size, void* d_ws, size_t ws_size,
                              hipStream_t stream) {
    rnnar_kernel<<<1024 / NBc, NTc, 0, stream>>>(
        (const int*)d_in[0],   (const float*)d_in[1],  (const float*)d_in[2],
        (const int*)d_in[3],   (const float*)d_in[4],  (const float*)d_in[5],
        (const float*)d_in[6],
        (const float*)d_in[7], (const float*)d_in[8],  (const float*)d_in[9],
        (const float*)d_in[10],(const float*)d_in[11], (const float*)d_in[12],
        (const float*)d_in[13],(const float*)d_in[14],
        (const float*)d_in[15],(const float*)d_in[16],
        (const float*)d_in[17],(const float*)d_in[18],
        (float*)d_out);
}

// Round 14
// 1749.927 us; speedup vs baseline: 1.3719x; 1.3719x over previous
//
#include <hip/hip_runtime.h>
#include <math.h>

typedef _Float16 half8 __attribute__((ext_vector_type(8)));
typedef _Float16 half4 __attribute__((ext_vector_type(4)));
typedef float float4v __attribute__((ext_vector_type(4)));

constexpr int Lc   = 2048;  // L_IN
constexpr int DECc = 64;    // DEC_LEN
constexpr int Hc   = 128;   // H
constexpr int EMBc = 16;    // EMB
constexpr int INc  = 18;    // IN_SIZE
constexpr int NBc  = 4;     // batches per block
constexpr int NTc  = 1024;  // 16 waves -> 4 waves/SIMD (R14)
constexpr int KT   = 5;     // k-tiles of 32 (z padded to 160)
constexpr int CARD = 200;
constexpr int ZS   = 160;   // z stride per batch (halves)
constexpr int SCW  = 40;    // per-wave shuffle scratch row stride (halves)

__device__ __forceinline__ float rcp_(float x) { return __builtin_amdgcn_rcpf(x); }
__device__ __forceinline__ float sigm(float x) { return rcp_(1.0f + __expf(-x)); }
__device__ __forceinline__ float tanh_(float x) { return 2.0f * rcp_(1.0f + __expf(-2.0f * x)) - 1.0f; }
__device__ __forceinline__ float softplus_(float x) { return __logf(1.0f + __expf(x)); }

// Transposed GEMM (verified R11/R13): D[m=batch(rep mod4)][n=gate] = z[m][k]*Wc^T[k][n],
// gate order g = 4*cell+gt. Wave wv owns gates [32wv, 32wv+32) = cells [8wv, 8wv+8).
// C layout: row = quad*4+reg, rows replicate batches mod 4 => any quad's reg r = batch r.

__global__ __launch_bounds__(NTc, 1) void rnnar_kernel(
    const int*   __restrict__ cat_in,  const float* __restrict__ cont_in,
    const float* __restrict__ X_in,    const int*   __restrict__ cat_out,
    const float* __restrict__ cont_out,const float* __restrict__ emb_table,
    const float* __restrict__ cont_w,
    const float* __restrict__ Wih_e, const float* __restrict__ Whh_e, const float* __restrict__ b_e,
    const float* __restrict__ Wih_d, const float* __restrict__ Whh_d, const float* __restrict__ b_d,
    const float* __restrict__ Wm, const float* __restrict__ bm,
    const float* __restrict__ Ws, const float* __restrict__ bs,
    const float* __restrict__ Wv, const float* __restrict__ bv,
    float* __restrict__ out)
{
    // ~61 KB total
    __shared__ _Float16      z_lds[2][NBc * ZS];   // 2.5 KB double-buffered z, [b][k]
    __shared__ _Float16      sc[16 * 4 * SCW];     // 5 KB  per-wave gate shuffle scratch
    __shared__ _Float16      emb_lds[CARD * EMBc]; // 6.4 KB
    __shared__ _Float16      xs0[NBc * Lc];        // 16 KB cont_in * w00
    __shared__ _Float16      xs1[NBc * Lc];        // 16 KB X_in
    __shared__ _Float16      xo_lds[NBc * DECc];   // 512 B cont_out * w00
    __shared__ unsigned char catb[NBc * Lc];       // 8 KB
    __shared__ unsigned char catob[NBc * DECc];    // 256 B
    __shared__ float         h32_lds[NBc * 132];   // 2.1 KB
    __shared__ float         wh_lds[6 * Hc];       // 3 KB
    __shared__ float         hb_lds[8];

    const int tid  = threadIdx.x;
    const int lane = tid & 63;
    const int wv   = tid >> 6;        // wave 0..15
    const int q    = lane >> 4;       // quad 0..3
    const int col  = lane & 15;
    const int b0   = blockIdx.x * NBc;
    const float w00 = cont_w[0];

    const int xk = tid >> 2, xb = tid & 3;   // x-writer role (tid < 72)
    const int cl = (lane >> 2) & 7;          // cell-local 0..7 (lanes 0-31 active)
    const int ab = lane & 3;                 // batch 0..3
    const int cell = 8 * wv + cl;            // activation cell (lanes < 32)
    const bool act_lane = (lane < 32);

    // ---------------- staging ----------------
    if (tid < NBc * ZS) {                     // zero both z buffers (as ints: 2*640 halves)
        ((int*)&z_lds[0][0])[tid] = 0;
    }
    for (int i = tid; i < NBc * Lc; i += NTc) {
        const int b = i >> 11, t = i & (Lc - 1);
        catb[i] = (unsigned char)cat_in[(b0 + b) * Lc + t];
        xs0[i]  = (_Float16)(cont_in[(b0 + b) * Lc + t] * w00);
        xs1[i]  = (_Float16)(X_in[(b0 + b) * Lc + t]);
    }
    if (tid < NBc * DECc) {
        const int b = tid >> 6, t = tid & 63;
        catob[tid]  = (unsigned char)cat_out[(b0 + b) * DECc + t];
        xo_lds[tid] = (_Float16)(cont_out[(b0 + b) * DECc + t] * w00);
    }
    for (int i = tid; i < CARD * EMBc; i += NTc) emb_lds[i] = (_Float16)emb_table[i];
    if (tid < 6 * Hc) {
        const int o = tid >> 7, k = tid & 127;
        wh_lds[tid] = (o == 0) ? Wm[k] : (o == 1) ? Ws[k] : Wv[(o - 2) * Hc + k];
    }
    if (tid == 0) { hb_lds[0] = bm[0]; hb_lds[1] = bs[0]; }
    if (tid < 4)  { hb_lds[2 + tid] = bv[tid]; }

    // ---- B-fragments: wave wv owns 2 gate-tiles (gates 32wv..32wv+31) ----
    half8 Bf[2][KT];
    float bias_s[2];
    #define LOAD_T(WIH, WHH, BB)                                               \
    {                                                                          \
        _Pragma("unroll")                                                      \
        for (int tile = 0; tile < 2; ++tile) {                                 \
            const int g   = 32 * wv + 16 * tile + col;                         \
            const int row = (g & 3) * Hc + (g >> 2);                           \
            _Pragma("unroll")                                                  \
            for (int kt = 0; kt < KT; ++kt) {                                  \
                half8 f;                                                       \
                _Pragma("unroll")                                              \
                for (int j = 0; j < 8; ++j) {                                  \
                    const int k = 32 * kt + 8 * q + j;                         \
                    float v = 0.0f;                                            \
                    if (k < INc)            v = WIH[row * INc + k];            \
                    else if (k < INc + Hc)  v = WHH[row * Hc + (k - INc)];     \
                    f[j] = (_Float16)v;                                        \
                }                                                              \
                Bf[tile][kt] = f;                                              \
            }                                                                  \
            bias_s[tile] = BB[row];                                            \
        }                                                                      \
    }

    LOAD_T(Wih_e, Whh_e, b_e);
    __syncthreads();

    // x(0) into buffer 0
    if (tid < INc * NBc) {
        _Float16 v;
        if (xk < EMBc)       v = emb_lds[(int)catb[xb * Lc] * EMBc + xk];
        else if (xk == EMBc) v = xs0[xb * Lc];
        else                 v = xs1[xb * Lc];
        z_lds[0][xb * ZS + xk] = v;
    }
    __syncthreads();

    int p = 0;
    float c_reg = 0.f;
    _Float16* scw = sc + wv * 4 * SCW;

    // ===================== encoder: 1 barrier/step =====================
    for (int t = 0; t < Lc; ++t) {
        const _Float16* zr = &z_lds[p][0];
        _Float16*       zw = &z_lds[p ^ 1][0];

        // A-frags from z (batch = col&3)
        const _Float16* ap = zr + (col & 3) * ZS + 8 * q;
        half8 Az[KT];
        #pragma unroll
        for (int kt = 0; kt < KT; ++kt) Az[kt] = *(const half8*)(ap + 32 * kt);

        float4v acc[2];
        #pragma unroll
        for (int tile = 0; tile < 2; ++tile) {
            float4v a = {bias_s[tile], bias_s[tile], bias_s[tile], bias_s[tile]};
            #pragma unroll
            for (int kt = 0; kt < KT; ++kt)
                a = __builtin_amdgcn_mfma_f32_16x16x32_f16(Az[kt], Bf[tile][kt], a, 0, 0, 0);
            acc[tile] = a;
        }

        // intra-wave shuffle: quad i (i<2) writes tile i's 4 batch-rows (reg r = batch r)
        #pragma unroll
        for (int tile = 0; tile < 2; ++tile) {
            if (q == tile) {
                #pragma unroll
                for (int r = 0; r < 4; ++r)
                    scw[r * SCW + 16 * tile + col] = (_Float16)acc[tile][r];
            }
        }
        // one cell-update per active lane: (cell, ab)
        if (act_lane) {
            const half4 g4 = *(const half4*)(scw + ab * SCW + 4 * cl);
            const float cn = sigm((float)g4[1]) * c_reg + sigm((float)g4[0]) * tanh_((float)g4[2]);
            c_reg = cn;
            zw[ab * ZS + INc + cell] = (_Float16)(sigm((float)g4[3]) * tanh_(cn));
        }

        // x(t+1) (clamped: t=Lc-1 writes decoder-init x)
        if (tid < INc * NBc) {
            const int t1 = (t + 1 < Lc) ? t + 1 : Lc - 1;
            _Float16 v;
            if (xk < EMBc)       v = emb_lds[(int)catb[xb * Lc + t1] * EMBc + xk];
            else if (xk == EMBc) v = xs0[xb * Lc + t1];
            else                 v = xs1[xb * Lc + t1];
            zw[xb * ZS + xk] = v;
        }
        __syncthreads();
        p ^= 1;
    }

    // ===================== decoder =====================
    LOAD_T(Wih_d, Whh_d, b_d);
    const float bm0 = hb_lds[0], bs0 = hb_lds[1];

    for (int t = 0; t < DECc; ++t) {
        const _Float16* zr = &z_lds[p][0];
        _Float16*       zw = &z_lds[p ^ 1][0];

        const _Float16* ap = zr + (col & 3) * ZS + 8 * q;
        half8 Az[KT];
        #pragma unroll
        for (int kt = 0; kt < KT; ++kt) Az[kt] = *(const half8*)(ap + 32 * kt);

        float4v acc[2];
        #pragma unroll
        for (int tile = 0; tile < 2; ++tile) {
            float4v a = {bias_s[tile], bias_s[tile], bias_s[tile], bias_s[tile]};
            #pragma unroll
            for (int kt = 0; kt < KT; ++kt)
                a = __builtin_amdgcn_mfma_f32_16x16x32_f16(Az[kt], Bf[tile][kt], a, 0, 0, 0);
            acc[tile] = a;
        }

        #pragma unroll
        for (int tile = 0; tile < 2; ++tile) {
            if (q == tile) {
                #pragma unroll
                for (int r = 0; r < 4; ++r)
                    scw[r * SCW + 16 * tile + col] = (_Float16)acc[tile][r];
            }
        }
        if (act_lane) {
            const half4 g4 = *(const half4*)(scw + ab * SCW + 4 * cl);
            const float cn = sigm((float)g4[1]) * c_reg + sigm((float)g4[0]) * tanh_((float)g4[2]);
            c_reg = cn;
            const float hv = sigm((float)g4[3]) * tanh_(cn);
            zw[ab * ZS + INc + cell] = (_Float16)hv;
            h32_lds[ab * 132 + cell] = hv;
        }

        // feats_out(t) -> x(t+1); slot 17 (mu) written by heads
        if (tid < INc * NBc && xk < INc - 1) {
            _Float16 v;
            if (xk < EMBc) v = emb_lds[(int)catob[xb * DECc + t] * EMBc + xk];
            else           v = xo_lds[xb * DECc + t];
            zw[xb * ZS + xk] = v;
        }
        __syncthreads();

        // heads
        if (tid < NBc * 8) {
            const int b = tid >> 3, o = tid & 7;
            if (o < 6) {
                float s = 0.0f;
                #pragma unroll 8
                for (int k = 0; k < Hc; ++k) s += wh_lds[o * Hc + k] * h32_lds[b * 132 + k];
                const int gb2 = b0 + b;
                if (o == 0) {
                    const float mu = s + bm0;
                    out[gb2 * DECc + t] = mu;
                    zw[b * ZS + (INc - 1)] = (_Float16)mu;   // mu feedback
                } else if (o == 1) {
                    out[65536 + gb2 * DECc + t] = softplus_(s + bs0);
                } else {
                    out[131072 + (gb2 * DECc + t) * 4 + (o - 2)] = s + hb_lds[2 + (o - 2)];
                }
            }
        }
        __syncthreads();
        p ^= 1;
    }
    #undef LOAD_T
}

extern "C" void kernel_launch(void* const* d_in, const int* in_sizes, int n_in,
                              void* d_out, int out_size, void* d_ws, size_t ws_size,
                              hipStream_t stream) {
    rnnar_kernel<<<1024 / NBc, NTc, 0, stream>>>(
        (const int*)d_in[0],   (const float*)d_in[1],  (const float*)d_in[2],
        (const int*)d_in[3],   (const float*)d_in[4],  (const float*)d_in[5],
        (const float*)d_in[6],
        (const float*)d_in[7], (const float*)d_in[8],  (const float*)d_in[9],
        (const float*)d_in[10],(const float*)d_in[11], (const float*)d_in[12],
        (const float*)d_in[13],(const float*)d_in[14],
        (const float*)d_in[15],(const float*)d_in[16],
        (const float*)d_in[17],(const float*)d_in[18],
        (float*)d_out);
}